// Round 9
// baseline (171.435 us; speedup 1.0000x reference)
//
#include <hip/hip_runtime.h>

typedef __attribute__((ext_vector_type(8))) short s8v;      // 8 bf16 (4 VGPR) MFMA operand
typedef __attribute__((ext_vector_type(16))) float f32x16;  // 32x32 MFMA accumulator

#define BB 32
#define SS 1024
#define DD 256
#define KB 16              // s-values per chunk (one K=16 MFMA step)
#define KHALF 512          // s-range per k-group (in-block k-split)
#define NCH (KHALF / KB)   // 32 chunks per k-group
#define LSTR 24            // shorts per feat-row: 48B (32B data+16B pad) -> per-quarter-wave
                           // residues 48f mod 128 have period 8 => 2-way = free (m136)
#define PSZ (64 * LSTR)    // plane: 1536 shorts
#define BUFSZ (6 * PSZ)    // 6 planes per k-group buffer: 9216 shorts = 18432 B
#define TOTSH (2 * BUFSZ)  // both k-groups: 36864 B static LDS

// out[b,a,c] = sum_s w * v_a * conj(v_c), v = r + j*i
// a-side planes (w-folded, hi/lo split): wr_h, wr_l, wi_h, wi_l
// c-side planes (RNE bf16):             r_c, i_c
// out_r = (wr_h+wr_l) x r_c + (wi_h+wi_l) x i_c      (accr)
// out_i = (wi_h+wi_l) x r_c - (wr_h+wr_l) x i_c      (acci - accx; separable per k-group)
// waves 0-3: s in [0,512); waves 4-7: s in [512,1024); merge via LDS exchange.

__device__ __forceinline__ unsigned short bf16rn(float v) {
    unsigned b = __float_as_uint(v);
    return (unsigned short)((b + 0x7FFFu + ((b >> 16) & 1u)) >> 16);
}

extern "C" __global__ void __launch_bounds__(512, 4)
cmix6_kernel(const float* __restrict__ real, const float* __restrict__ imag,
             const float* __restrict__ wts, float* __restrict__ out) {
    __shared__ unsigned short lds[TOTSH];   // 36864 B -> VGPR-limited 2 blocks/CU, 16 waves/CU

    // XCD swizzle: 512 = 8 XCDs x 64 slots; 4 batches per XCD (L2 reuse)
    const int bx   = blockIdx.x;
    const int xcd  = bx & 7;
    const int slot = bx >> 3;
    const int b    = xcd * 4 + (slot >> 4);
    const int t    = slot & 15;
    const int a0   = (t >> 2) * 64;
    const int c0   = (t & 3) * 64;

    const int tid = threadIdx.x;
    const int wid = tid >> 6;      // 0..7
    const int kg  = wid >> 2;      // k-group: 0 or 1
    const int wq  = wid & 3;       // role / tile-wave within k-group
    const int l   = tid & 63;

    // staging role (per k-group): wq0->wr(h,l), wq1->wi(h,l), wq2->r_c, wq3->i_c
    const int  fgrp = l >> 2;      // 16 feat-quads
    const int  sgrp = l & 3;       // 4 s-quads of 4
    const bool isA  = (wq < 2);
    const float* srcA = ((wq & 1) ? imag : real)
                      + (size_t)b * SS * DD + (isA ? a0 : c0) + fgrp * 4;
    const float* wb = wts + (size_t)b * SS;
    const int pA = wq * 2 * PSZ;            // hi plane; lo at +PSZ
    const int pC = (4 + (wq & 1)) * PSZ;

    // compute role: 2x2 wave grid of 32x32 subtiles (same wq -> same subtile in both kg)
    const int m0  = (wq >> 1) * 32;
    const int n0  = (wq & 1) * 32;
    const int fr  = l & 31;
    const int hi8 = (l >> 5) * 8;

    unsigned short* klds = lds + kg * BUFSZ;
    const int sbeg = kg * KHALF;

    f32x16 accr = {}, acci = {}, accx = {};
    float4 xr[4];   // in-flight staged rows (static-indexed only)

    auto stage_load = [&](int ch) {
        const int sh = sbeg + ch * KB + sgrp * 4;
        #pragma unroll
        for (int si = 0; si < 4; ++si)
            xr[si] = *(const float4*)(srcA + (size_t)(sh + si) * DD);
    };

    auto stage_store = [&](int ch) {
        const int sh = sbeg + ch * KB + sgrp * 4;
        const float xs[4][4] = {
            {xr[0].x, xr[0].y, xr[0].z, xr[0].w},
            {xr[1].x, xr[1].y, xr[1].z, xr[1].w},
            {xr[2].x, xr[2].y, xr[2].z, xr[2].w},
            {xr[3].x, xr[3].y, xr[3].z, xr[3].w}};
        if (isA) {
            const float4 w4 = *(const float4*)(wb + sh);
            const float wv[4] = {w4.x, w4.y, w4.z, w4.w};
            #pragma unroll
            for (int e = 0; e < 4; ++e) {
                unsigned hs[4], ls[4];
                #pragma unroll
                for (int si = 0; si < 4; ++si) {
                    const float y     = xs[si][e] * wv[si];
                    const unsigned yb = __float_as_uint(y);
                    const unsigned hb = yb & 0xFFFF0000u;            // truncated hi
                    const float    lo = y - __uint_as_float(hb);     // exact residual
                    hs[si] = hb >> 16;
                    ls[si] = __float_as_uint(lo) >> 16;              // truncated lo
                }
                const int off = pA + (fgrp * 4 + e) * LSTR + sgrp * 4;
                uint2 vh = {hs[0] | (hs[1] << 16), hs[2] | (hs[3] << 16)};
                uint2 vl = {ls[0] | (ls[1] << 16), ls[2] | (ls[3] << 16)};
                *(uint2*)&klds[off]       = vh;
                *(uint2*)&klds[off + PSZ] = vl;
            }
        } else {
            #pragma unroll
            for (int e = 0; e < 4; ++e) {
                unsigned cs[4];
                #pragma unroll
                for (int si = 0; si < 4; ++si) cs[si] = bf16rn(xs[si][e]);  // RNE
                const int off = pC + (fgrp * 4 + e) * LSTR + sgrp * 4;
                uint2 v = {cs[0] | (cs[1] << 16), cs[2] | (cs[3] << 16)};
                *(uint2*)&klds[off] = v;
            }
        }
    };

    // ---- prologue ----
    stage_load(0);

    // ---- main loop: store(ch); bar; issue load(ch+1); MFMA(ch); bar ----
    for (int ch = 0; ch < NCH; ++ch) {
        stage_store(ch);
        __syncthreads();
        if (ch + 1 < NCH) stage_load(ch + 1);   // HBM latency hides under MFMA

        const int ra = (m0 + fr) * LSTR + hi8;
        const int rc = (n0 + fr) * LSTR + hi8;
        s8v A1 = *(const s8v*)&klds[0 * PSZ + ra];   // wr_h
        s8v A2 = *(const s8v*)&klds[1 * PSZ + ra];   // wr_l
        s8v A3 = *(const s8v*)&klds[2 * PSZ + ra];   // wi_h
        s8v A4 = *(const s8v*)&klds[3 * PSZ + ra];   // wi_l
        s8v C1 = *(const s8v*)&klds[4 * PSZ + rc];   // r_c
        s8v C2 = *(const s8v*)&klds[5 * PSZ + rc];   // i_c
        accr = __builtin_amdgcn_mfma_f32_32x32x16_bf16(A1, C1, accr, 0, 0, 0);
        accr = __builtin_amdgcn_mfma_f32_32x32x16_bf16(A2, C1, accr, 0, 0, 0);
        accr = __builtin_amdgcn_mfma_f32_32x32x16_bf16(A3, C2, accr, 0, 0, 0);
        accr = __builtin_amdgcn_mfma_f32_32x32x16_bf16(A4, C2, accr, 0, 0, 0);
        acci = __builtin_amdgcn_mfma_f32_32x32x16_bf16(A3, C1, acci, 0, 0, 0);
        acci = __builtin_amdgcn_mfma_f32_32x32x16_bf16(A4, C1, acci, 0, 0, 0);
        accx = __builtin_amdgcn_mfma_f32_32x32x16_bf16(A1, C2, accx, 0, 0, 0);
        accx = __builtin_amdgcn_mfma_f32_32x32x16_bf16(A2, C2, accx, 0, 0, 0);

        __syncthreads();
    }

    // ---- k-group merge: per-kg (orr, oii) are separable; exchange [reg][256] ----
    float* ex = (float*)lds;           // 32 regs x 256 lanes x 4B = 32768 B (<= 36864)
    const int gl = wq * 64 + l;        // 0..255
    if (kg == 1) {
        #pragma unroll
        for (int j = 0; j < 16; ++j) {
            ex[j * 256 + gl]        = accr[j];
            ex[(16 + j) * 256 + gl] = acci[j] - accx[j];
        }
    }
    __syncthreads();
    if (kg == 0) {
        // epilogue: C/D layout col=lane&31, row=(reg&3)+8*(reg>>2)+4*(lane>>5)
        float* outR = out + (size_t)b * DD * DD;
        float* outI = out + (size_t)BB * DD * DD + (size_t)b * DD * DD;
        const int col = c0 + n0 + (l & 31);
        #pragma unroll
        for (int g = 0; g < 4; ++g) {
            #pragma unroll
            for (int q = 0; q < 4; ++q) {
                const int reg = g * 4 + q;
                const int row = a0 + m0 + q + 8 * g + 4 * (l >> 5);
                const float orr = accr[reg] + ex[reg * 256 + gl];
                const float oii = (acci[reg] - accx[reg]) + ex[(16 + reg) * 256 + gl];
                outR[(size_t)row * DD + col] = orr;
                outI[(size_t)row * DD + col] = oii;
            }
        }
    }
}

extern "C" void kernel_launch(void* const* d_in, const int* in_sizes, int n_in,
                              void* d_out, int out_size, void* d_ws, size_t ws_size,
                              hipStream_t stream) {
    const float* real = (const float*)d_in[0];
    const float* imag = (const float*)d_in[1];
    const float* wts  = (const float*)d_in[2];
    float* out = (float*)d_out;
    dim3 grid(512);    // 8 XCDs x (4 batches x 16 tiles) = 2 blocks/CU
    dim3 block(512);   // 8 waves: 2 k-groups x 4 tile-waves -> 4 waves/SIMD resident
    cmix6_kernel<<<grid, block, 0, stream>>>(real, imag, wts, out);
}